// Round 5
// baseline (1151.881 us; speedup 1.0000x reference)
//
#include <hip/hip_runtime.h>
#include <cstddef>
#include <cstdint>

// Stacked SimpleRNN, fp32.  B=512, T=512, F=78, hiddens 16/32/64/70, dense->5+softmax.
//
// Round-5 structure (6 dispatches):
//   proj0  : GEMM xw0 = x @ W0 + b0            [M,78]x[78,16]
//   R0     : fused scan L0 (H=16, 4 rows/wave) + on-the-fly xw1 = h0 @ W1 + b1
//   R1     : fused scan L1 (H=32, 2 rows/wave) + on-the-fly xw2 = h1 @ W2 + b2
//   rec64  : scan L2 (H=64, 1 row/wave) -> h2 sequence
//   proj3  : GEMM xw3 = h2 @ W3 + b3           [M,64]x[64,70]
//   rec70  : 2-wave scan L3 (one column/lane, h double-buffered in LDS,
//            1 barrier/step) + fused dense(70->5) + softmax
//
// Round-4 lesson: rec70's dual-column single-wave design needed 144 pinned
// VGPRs -> RA capped at 128 and spilled U to scratch -> 281 us (unchanged).
// The 2-wave design needs only u[72] per lane.

#define BB 512
#define TT 512
#define M_TOTAL (BB * TT)

// LDS-visibility sync WITHOUT a vmcnt drain (keeps global prefetch in flight).
#define LDS_BARRIER() asm volatile("s_waitcnt lgkmcnt(0)\n\ts_barrier" ::: "memory")

__device__ __forceinline__ float tanh_fast(float x) {
  float ax = fabsf(x);
  float e = __expf(ax + ax);
  float r = 1.0f - 2.0f / (e + 1.0f);
  return (x >= 0.0f) ? r : -r;
}

__device__ __forceinline__ void fma4(float4& a, float s, const float4 w) {
  a.x = fmaf(s, w.x, a.x);
  a.y = fmaf(s, w.y, a.y);
  a.z = fmaf(s, w.z, a.z);
  a.w = fmaf(s, w.w, a.w);
}

// ---------------------------------------------------------------------------
// proj: out[M,N] = in[M,K] @ W[K,N] + b.  256 threads; 4x4 tile per thread.
// ---------------------------------------------------------------------------
template<int K, int N, int CG>
__global__ __launch_bounds__(256)
void proj_kernel(const float* __restrict__ in, const float* __restrict__ W,
                 const float* __restrict__ bias, float* __restrict__ out, int M)
{
  constexpr int NP = CG * 4;
  constexpr int RG = 256 / CG;  // active row-groups
  __shared__ __align__(16) float wlds[K][NP];
  __shared__ __align__(16) float blds[NP];
  const int tid = threadIdx.x;
  for (int idx = tid; idx < K * NP; idx += 256) {
    int k = idx / NP, jj = idx - k * NP;
    wlds[k][jj] = (jj < N) ? W[k * N + jj] : 0.0f;
  }
  if (tid < NP) blds[tid] = (tid < N) ? bias[tid] : 0.0f;
  __syncthreads();

  const int c = tid % CG;
  const int rg = tid / CG;
  if (rg >= RG) return;  // no barriers after this point
  const int j0 = c * 4;
  const long row0 = (long)blockIdx.x * (RG * 4) + (long)rg * 4;

  float4 b4 = *reinterpret_cast<const float4*>(&blds[j0]);
  float4 acc[4] = {b4, b4, b4, b4};
  const float* inp[4];
  bool rv[4];
  #pragma unroll
  for (int rr = 0; rr < 4; ++rr) {
    long rowi = row0 + rr;
    rv[rr] = rowi < M;
    inp[rr] = in + (rv[rr] ? rowi : 0) * (long)K;
  }

  int k = 0;
  for (; k + 4 <= K; k += 4) {
    float4 w0 = *reinterpret_cast<const float4*>(&wlds[k + 0][j0]);
    float4 w1 = *reinterpret_cast<const float4*>(&wlds[k + 1][j0]);
    float4 w2 = *reinterpret_cast<const float4*>(&wlds[k + 2][j0]);
    float4 w3 = *reinterpret_cast<const float4*>(&wlds[k + 3][j0]);
    #pragma unroll
    for (int rr = 0; rr < 4; ++rr) {
      float2 i0 = *reinterpret_cast<const float2*>(inp[rr] + k);
      float2 i1 = *reinterpret_cast<const float2*>(inp[rr] + k + 2);
      fma4(acc[rr], i0.x, w0);
      fma4(acc[rr], i0.y, w1);
      fma4(acc[rr], i1.x, w2);
      fma4(acc[rr], i1.y, w3);
    }
  }
  for (; k < K; ++k) {  // K tail (K=78)
    float4 w0 = *reinterpret_cast<const float4*>(&wlds[k][j0]);
    #pragma unroll
    for (int rr = 0; rr < 4; ++rr) fma4(acc[rr], inp[rr][k], w0);
  }

  #pragma unroll
  for (int rr = 0; rr < 4; ++rr) {
    if (!rv[rr]) continue;
    long obase = (row0 + rr) * (long)N + j0;
    if constexpr ((N % 4) == 0) {
      *reinterpret_cast<float4*>(&out[obase]) = acc[rr];
    } else {
      if (j0 + 4 <= N) {
        *reinterpret_cast<float2*>(&out[obase]) = make_float2(acc[rr].x, acc[rr].y);
        *reinterpret_cast<float2*>(&out[obase + 2]) = make_float2(acc[rr].z, acc[rr].w);
      } else {
        float v[4] = {acc[rr].x, acc[rr].y, acc[rr].z, acc[rr].w};
        #pragma unroll
        for (int jj = 0; jj < 4; ++jj)
          if (j0 + jj < N) out[obase + jj] = v[jj];
      }
    }
  }
}

// ---------------------------------------------------------------------------
// R0: fused scan H=16 (4 rows per single wave) + projection to HN=32.
// Lane (r=tid/16, j=tid%16) runs the recurrence for (row r, col j).
// Proj: lane computes xw1[rows 2pr,2pr+1][t][c], c=tid%32, pr=tid/32, reading
// the freshly written h_t from LDS (in-order DS within one wave).
// ---------------------------------------------------------------------------
__global__ __launch_bounds__(64, 1)
void fused_rec16(const float* __restrict__ xw, const float* __restrict__ U,
                 const float* __restrict__ Wn, const float* __restrict__ bn,
                 float* __restrict__ xwn)
{
  constexpr int H = 16, ROWS = 4, HN = 32, PF = 8;
  const int tid = threadIdx.x;
  const int r = tid >> 4, j = tid & 15;
  const int c = tid & 31, pr = tid >> 5;
  __shared__ __align__(16) float hlds[ROWS][H];
  for (int i = tid; i < ROWS * H; i += 64) reinterpret_cast<float*>(hlds)[i] = 0.0f;
  __syncthreads();

  float u[H], w[H];
  #pragma unroll
  for (int kk = 0; kk < H; ++kk) {
    u[kk] = U[kk * H + j];
    w[kk] = Wn[kk * HN + c];
    asm volatile("" : "+v"(u[kk]), "+v"(w[kk]));
  }
  const float bc = bn[c];

  const float* xwrow = xw + ((size_t)(blockIdx.x * ROWS + r) * TT) * H + j;
  float* o0 = xwn + ((size_t)(blockIdx.x * ROWS + 2 * pr + 0) * TT) * HN + c;
  float* o1 = xwn + ((size_t)(blockIdx.x * ROWS + 2 * pr + 1) * TT) * HN + c;

  float pf[PF];
  #pragma unroll
  for (int d = 0; d < PF; ++d) pf[d] = xwrow[(size_t)d * H];

  for (int t = 0; t < TT; t += PF) {
    #pragma unroll
    for (int d = 0; d < PF; ++d) {
      float xv = pf[d];
      int tn = t + d + PF;
      tn = (tn < TT) ? tn : (TT - 1);
      pf[d] = xwrow[(size_t)tn * H];

      const float* hb = &hlds[r][0];
      float a0 = xv, a1 = 0.0f, a2 = 0.0f, a3 = 0.0f;
      #pragma unroll
      for (int k4 = 0; k4 < H / 4; ++k4) {
        float4 h4 = *reinterpret_cast<const float4*>(hb + 4 * k4);
        a0 = fmaf(h4.x, u[4 * k4 + 0], a0);
        a1 = fmaf(h4.y, u[4 * k4 + 1], a1);
        a2 = fmaf(h4.z, u[4 * k4 + 2], a2);
        a3 = fmaf(h4.w, u[4 * k4 + 3], a3);
      }
      float hn = tanh_fast((a0 + a1) + (a2 + a3));
      hlds[r][j] = hn;  // all 64 lanes' writes complete before next DS instr

      // projection: uses h_t of rows 2pr, 2pr+1 (just written)
      const float* h0b = &hlds[2 * pr + 0][0];
      const float* h1b = &hlds[2 * pr + 1][0];
      float s0 = bc, s1 = bc, s2 = 0.0f, s3 = 0.0f;
      #pragma unroll
      for (int k4 = 0; k4 < H / 4; ++k4) {
        float4 ha = *reinterpret_cast<const float4*>(h0b + 4 * k4);
        float4 hc = *reinterpret_cast<const float4*>(h1b + 4 * k4);
        s0 = fmaf(ha.x, w[4 * k4 + 0], s0);
        s2 = fmaf(ha.y, w[4 * k4 + 1], s2);
        s0 = fmaf(ha.z, w[4 * k4 + 2], s0);
        s2 = fmaf(ha.w, w[4 * k4 + 3], s2);
        s1 = fmaf(hc.x, w[4 * k4 + 0], s1);
        s3 = fmaf(hc.y, w[4 * k4 + 1], s3);
        s1 = fmaf(hc.z, w[4 * k4 + 2], s1);
        s3 = fmaf(hc.w, w[4 * k4 + 3], s3);
      }
      o0[(size_t)(t + d) * HN] = s0 + s2;  // fire-and-forget
      o1[(size_t)(t + d) * HN] = s1 + s3;
    }
  }
}

// ---------------------------------------------------------------------------
// R1: fused scan H=32 (2 rows per single wave) + projection to HN=64.
// Lane (r=tid/32, j=tid%32) runs the recurrence.  Proj: lane owns output
// column c=tid for BOTH rows (one W-column = 32 regs serves 2 outputs).
// ---------------------------------------------------------------------------
__global__ __launch_bounds__(64, 1)
void fused_rec32(const float* __restrict__ xw, const float* __restrict__ U,
                 const float* __restrict__ Wn, const float* __restrict__ bn,
                 float* __restrict__ xwn)
{
  constexpr int H = 32, ROWS = 2, HN = 64, PF = 8;
  const int tid = threadIdx.x;
  const int r = tid >> 5, j = tid & 31;
  const int c = tid;
  __shared__ __align__(16) float hlds[ROWS][H];
  for (int i = tid; i < ROWS * H; i += 64) reinterpret_cast<float*>(hlds)[i] = 0.0f;
  __syncthreads();

  float u[H], w[H];
  #pragma unroll
  for (int kk = 0; kk < H; ++kk) {
    u[kk] = U[kk * H + j];
    w[kk] = Wn[kk * HN + c];
    asm volatile("" : "+v"(u[kk]), "+v"(w[kk]));
  }
  const float bc = bn[c];

  const float* xwrow = xw + ((size_t)(blockIdx.x * ROWS + r) * TT) * H + j;
  float* o0 = xwn + ((size_t)(blockIdx.x * ROWS + 0) * TT) * HN + c;
  float* o1 = xwn + ((size_t)(blockIdx.x * ROWS + 1) * TT) * HN + c;

  float pf[PF];
  #pragma unroll
  for (int d = 0; d < PF; ++d) pf[d] = xwrow[(size_t)d * H];

  for (int t = 0; t < TT; t += PF) {
    #pragma unroll
    for (int d = 0; d < PF; ++d) {
      float xv = pf[d];
      int tn = t + d + PF;
      tn = (tn < TT) ? tn : (TT - 1);
      pf[d] = xwrow[(size_t)tn * H];

      const float* hb = &hlds[r][0];
      float a0 = xv, a1 = 0.0f, a2 = 0.0f, a3 = 0.0f;
      #pragma unroll
      for (int k4 = 0; k4 < H / 4; ++k4) {
        float4 h4 = *reinterpret_cast<const float4*>(hb + 4 * k4);
        a0 = fmaf(h4.x, u[4 * k4 + 0], a0);
        a1 = fmaf(h4.y, u[4 * k4 + 1], a1);
        a2 = fmaf(h4.z, u[4 * k4 + 2], a2);
        a3 = fmaf(h4.w, u[4 * k4 + 3], a3);
      }
      float hn = tanh_fast((a0 + a1) + (a2 + a3));
      hlds[r][j] = hn;

      // projection: both rows' h_t (just written)
      const float* h0b = &hlds[0][0];
      const float* h1b = &hlds[1][0];
      float s0 = bc, s1 = bc, s2 = 0.0f, s3 = 0.0f;
      #pragma unroll
      for (int k4 = 0; k4 < H / 4; ++k4) {
        float4 ha = *reinterpret_cast<const float4*>(h0b + 4 * k4);
        float4 hc = *reinterpret_cast<const float4*>(h1b + 4 * k4);
        s0 = fmaf(ha.x, w[4 * k4 + 0], s0);
        s2 = fmaf(ha.y, w[4 * k4 + 1], s2);
        s0 = fmaf(ha.z, w[4 * k4 + 2], s0);
        s2 = fmaf(ha.w, w[4 * k4 + 3], s2);
        s1 = fmaf(hc.x, w[4 * k4 + 0], s1);
        s3 = fmaf(hc.y, w[4 * k4 + 1], s3);
        s1 = fmaf(hc.z, w[4 * k4 + 2], s1);
        s3 = fmaf(hc.w, w[4 * k4 + 3], s3);
      }
      o0[(size_t)(t + d) * HN] = s0 + s2;
      o1[(size_t)(t + d) * HN] = s1 + s3;
    }
  }
}

// ---------------------------------------------------------------------------
// rec64: plain scan H=64, 1 row per single wave.  Outputs h sequence.
// ---------------------------------------------------------------------------
__global__ __launch_bounds__(64, 1)
void rec64_kernel(const float* __restrict__ xw, const float* __restrict__ U,
                  float* __restrict__ hseq)
{
  constexpr int H = 64, PF = 8;
  const int tid = threadIdx.x;
  const int row = blockIdx.x;

  __shared__ __align__(16) float hlds[H];
  hlds[tid] = 0.0f;
  __syncthreads();

  float u[H];
  #pragma unroll
  for (int kk = 0; kk < H; ++kk) {
    u[kk] = U[kk * H + tid];
    asm volatile("" : "+v"(u[kk]));
  }

  const float* xwrow = xw + ((size_t)row * TT) * H + tid;
  float* hout = hseq + ((size_t)row * TT) * H + tid;

  float pf[PF];
  #pragma unroll
  for (int d = 0; d < PF; ++d) pf[d] = xwrow[(size_t)d * H];

  for (int t = 0; t < TT; t += PF) {
    #pragma unroll
    for (int d = 0; d < PF; ++d) {
      float xv = pf[d];
      int tn = t + d + PF;
      tn = (tn < TT) ? tn : (TT - 1);
      pf[d] = xwrow[(size_t)tn * H];

      float a0 = xv, a1 = 0.0f, a2 = 0.0f, a3 = 0.0f;
      #pragma unroll
      for (int k4 = 0; k4 < H / 4; ++k4) {
        float4 h4 = *reinterpret_cast<const float4*>(&hlds[4 * k4]);
        a0 = fmaf(h4.x, u[4 * k4 + 0], a0);
        a1 = fmaf(h4.y, u[4 * k4 + 1], a1);
        a2 = fmaf(h4.z, u[4 * k4 + 2], a2);
        a3 = fmaf(h4.w, u[4 * k4 + 3], a3);
      }
      float hn = tanh_fast((a0 + a1) + (a2 + a3));
      hlds[tid] = hn;
      hout[(size_t)(t + d) * H] = hn;
    }
  }
}

// ---------------------------------------------------------------------------
// rec70: 2-wave (128-thread) scan H=70, one column per lane (70 active).
// h double-buffered in LDS, one lgkmcnt+s_barrier per step (no vmcnt drain;
// this kernel has no global stores in the loop, so prefetch stays 8 deep).
// Fused dense(70->5) + softmax at the end.
// ---------------------------------------------------------------------------
__global__ __launch_bounds__(128, 1)
void rec70_kernel(const float* __restrict__ xw, const float* __restrict__ U,
                  const float* __restrict__ Wd, const float* __restrict__ bd,
                  float* __restrict__ outp)
{
  constexpr int H = 70, HP = 72, PF = 8;
  const int tid = threadIdx.x;
  const int row = blockIdx.x;
  const bool act = tid < H;
  const int j = act ? tid : 0;

  __shared__ __align__(16) float hbuf[2][HP];
  for (int i = tid; i < 2 * HP; i += 128) reinterpret_cast<float*>(hbuf)[i] = 0.0f;
  __syncthreads();

  float u[HP];
  #pragma unroll
  for (int kk = 0; kk < HP; ++kk) {
    u[kk] = (kk < H && act) ? U[kk * H + j] : 0.0f;
    asm volatile("" : "+v"(u[kk]));
  }

  const float* xwrow = xw + ((size_t)row * TT) * H + j;
  float pf[PF];
  #pragma unroll
  for (int d = 0; d < PF; ++d) pf[d] = xwrow[(size_t)d * H];

  for (int t = 0; t < TT; t += PF) {
    #pragma unroll
    for (int d = 0; d < PF; ++d) {
      float xv = pf[d];
      int tn = t + d + PF;
      tn = (tn < TT) ? tn : (TT - 1);
      pf[d] = xwrow[(size_t)tn * H];

      const float* hb = &hbuf[(t + d) & 1][0];
      float a0 = xv, a1 = 0.0f, a2 = 0.0f, a3 = 0.0f;
      #pragma unroll
      for (int k4 = 0; k4 < HP / 4; ++k4) {
        float4 h4 = *reinterpret_cast<const float4*>(hb + 4 * k4);
        a0 = fmaf(h4.x, u[4 * k4 + 0], a0);
        a1 = fmaf(h4.y, u[4 * k4 + 1], a1);
        a2 = fmaf(h4.z, u[4 * k4 + 2], a2);
        a3 = fmaf(h4.w, u[4 * k4 + 3], a3);
      }
      float hn = tanh_fast((a0 + a1) + (a2 + a3));
      if (act) hbuf[((t + d) & 1) ^ 1][j] = hn;  // write next-state buffer
      LDS_BARRIER();
    }
  }

  // TT even -> final h is in hbuf[0].  Dense (70->5) + softmax in wave 0.
  float l = 0.0f;
  if (tid < 5) {
    l = bd[tid];
    #pragma unroll
    for (int kk = 0; kk < H; ++kk)
      l = fmaf(hbuf[0][kk], Wd[kk * 5 + tid], l);
  }
  float l0 = __shfl(l, 0), l1 = __shfl(l, 1), l2 = __shfl(l, 2),
        l3 = __shfl(l, 3), l4 = __shfl(l, 4);
  float m = fmaxf(fmaxf(fmaxf(l0, l1), fmaxf(l2, l3)), l4);
  float s = __expf(l0 - m) + __expf(l1 - m) + __expf(l2 - m) +
            __expf(l3 - m) + __expf(l4 - m);
  if (tid < 5)
    outp[(size_t)row * 5 + tid] = __expf(l - m) / s;
}

extern "C" void kernel_launch(void* const* d_in, const int* in_sizes, int n_in,
                              void* d_out, int out_size, void* d_ws, size_t ws_size,
                              hipStream_t stream)
{
  const float* x  = (const float*)d_in[0];
  const float* W0 = (const float*)d_in[1];
  const float* U0 = (const float*)d_in[2];
  const float* b0 = (const float*)d_in[3];
  const float* W1 = (const float*)d_in[4];
  const float* U1 = (const float*)d_in[5];
  const float* b1 = (const float*)d_in[6];
  const float* W2 = (const float*)d_in[7];
  const float* U2 = (const float*)d_in[8];
  const float* b2 = (const float*)d_in[9];
  const float* W3 = (const float*)d_in[10];
  const float* U3 = (const float*)d_in[11];
  const float* b3 = (const float*)d_in[12];
  const float* Wd = (const float*)d_in[13];
  const float* bd = (const float*)d_in[14];
  float* outp = (float*)d_out;

  // A: xw0 [M,16] -> xw2 [M,64] -> xw3 [M,70] (73,400,320 B)
  // Bv: xw1 [M,32] -> h2 [M,64]               (67,108,864 B)
  float* A  = (float*)d_ws;
  float* Bv = (float*)((char*)d_ws + 73400320);

  const int M = M_TOTAL;

  // xw0 = x @ W0 + b0
  proj_kernel<78, 16, 4><<<M / 256, 256, 0, stream>>>(x, W0, b0, A, M);
  // scan L0 + fused xw1 = h0 @ W1 + b1
  fused_rec16<<<BB / 4, 64, 0, stream>>>(A, U0, W1, b1, Bv);
  // scan L1 + fused xw2 = h1 @ W2 + b2
  fused_rec32<<<BB / 2, 64, 0, stream>>>(Bv, U1, W2, b2, A);
  // scan L2 -> h2 sequence
  rec64_kernel<<<BB, 64, 0, stream>>>(A, U2, Bv);
  // xw3 = h2 @ W3 + b3
  proj_kernel<64, 70, 18><<<(M + 55) / 56, 256, 0, stream>>>(Bv, W3, b3, A, M);
  // scan L3 (2-wave) + dense + softmax
  rec70_kernel<<<BB, 128, 0, stream>>>(A, U3, Wd, bd, outp);
}

// Round 6
// 990.205 us; speedup vs baseline: 1.1633x; 1.1633x over previous
//
#include <hip/hip_runtime.h>
#include <cstddef>
#include <cstdint>

// Stacked SimpleRNN, fp32.  B=512, T=512, F=78, hiddens 16/32/64/70, dense->5+softmax.
//
// Structure (6 dispatches):
//   proj0  : GEMM xw0 = x @ W0 + b0            [M,78]x[78,16]
//   R0     : fused scan L0 (H=16, 4 rows/wave) + on-the-fly xw1 = h0 @ W1 + b1
//   R1     : fused scan L1 (H=32, 2 rows/wave) + on-the-fly xw2 = h1 @ W2 + b2
//   rec64  : scan L2 (H=64, 1 row/wave) -> h2 sequence
//   proj3  : GEMM xw3 = h2 @ W3 + b3           [M,64]x[64,70]
//   rec70  : 2-wave scan L3 + fused dense(70->5) + softmax
//
// Round-5 lesson: __launch_bounds__(N,1) sets only the MIN waves/EU; the RA still
// targets 8 waves/EU -> 56-64 VGPR budget -> U/W spilled to scratch -> ~1500
// cyc/step latency wall (H-independent, seen rounds 2-5).  The fix is
// amdgpu_waves_per_eu(1,1): max waves/EU = 1 -> full 512-VGPR budget.
#define REC_ATTR __attribute__((amdgpu_waves_per_eu(1, 1)))

#define BB 512
#define TT 512
#define M_TOTAL (BB * TT)

// LDS-visibility sync WITHOUT a vmcnt drain (keeps global prefetch in flight).
#define LDS_BARRIER() asm volatile("s_waitcnt lgkmcnt(0)\n\ts_barrier" ::: "memory")

__device__ __forceinline__ float tanh_fast(float x) {
  float ax = fabsf(x);
  float e = __expf(ax + ax);
  float r = 1.0f - 2.0f / (e + 1.0f);
  return (x >= 0.0f) ? r : -r;
}

__device__ __forceinline__ void fma4(float4& a, float s, const float4 w) {
  a.x = fmaf(s, w.x, a.x);
  a.y = fmaf(s, w.y, a.y);
  a.z = fmaf(s, w.z, a.z);
  a.w = fmaf(s, w.w, a.w);
}

// ---------------------------------------------------------------------------
// proj: out[M,N] = in[M,K] @ W[K,N] + b.  256 threads; 4x4 tile per thread.
// (multi-wave, memory-bound: default occupancy heuristics are fine here)
// ---------------------------------------------------------------------------
template<int K, int N, int CG>
__global__ __launch_bounds__(256)
void proj_kernel(const float* __restrict__ in, const float* __restrict__ W,
                 const float* __restrict__ bias, float* __restrict__ out, int M)
{
  constexpr int NP = CG * 4;
  constexpr int RG = 256 / CG;  // active row-groups
  __shared__ __align__(16) float wlds[K][NP];
  __shared__ __align__(16) float blds[NP];
  const int tid = threadIdx.x;
  for (int idx = tid; idx < K * NP; idx += 256) {
    int k = idx / NP, jj = idx - k * NP;
    wlds[k][jj] = (jj < N) ? W[k * N + jj] : 0.0f;
  }
  if (tid < NP) blds[tid] = (tid < N) ? bias[tid] : 0.0f;
  __syncthreads();

  const int c = tid % CG;
  const int rg = tid / CG;
  if (rg >= RG) return;  // no barriers after this point
  const int j0 = c * 4;
  const long row0 = (long)blockIdx.x * (RG * 4) + (long)rg * 4;

  float4 b4 = *reinterpret_cast<const float4*>(&blds[j0]);
  float4 acc[4] = {b4, b4, b4, b4};
  const float* inp[4];
  bool rv[4];
  #pragma unroll
  for (int rr = 0; rr < 4; ++rr) {
    long rowi = row0 + rr;
    rv[rr] = rowi < M;
    inp[rr] = in + (rv[rr] ? rowi : 0) * (long)K;
  }

  int k = 0;
  for (; k + 4 <= K; k += 4) {
    float4 w0 = *reinterpret_cast<const float4*>(&wlds[k + 0][j0]);
    float4 w1 = *reinterpret_cast<const float4*>(&wlds[k + 1][j0]);
    float4 w2 = *reinterpret_cast<const float4*>(&wlds[k + 2][j0]);
    float4 w3 = *reinterpret_cast<const float4*>(&wlds[k + 3][j0]);
    #pragma unroll
    for (int rr = 0; rr < 4; ++rr) {
      float2 i0 = *reinterpret_cast<const float2*>(inp[rr] + k);
      float2 i1 = *reinterpret_cast<const float2*>(inp[rr] + k + 2);
      fma4(acc[rr], i0.x, w0);
      fma4(acc[rr], i0.y, w1);
      fma4(acc[rr], i1.x, w2);
      fma4(acc[rr], i1.y, w3);
    }
  }
  for (; k < K; ++k) {  // K tail (K=78)
    float4 w0 = *reinterpret_cast<const float4*>(&wlds[k][j0]);
    #pragma unroll
    for (int rr = 0; rr < 4; ++rr) fma4(acc[rr], inp[rr][k], w0);
  }

  #pragma unroll
  for (int rr = 0; rr < 4; ++rr) {
    if (!rv[rr]) continue;
    long obase = (row0 + rr) * (long)N + j0;
    if constexpr ((N % 4) == 0) {
      *reinterpret_cast<float4*>(&out[obase]) = acc[rr];
    } else {
      if (j0 + 4 <= N) {
        *reinterpret_cast<float2*>(&out[obase]) = make_float2(acc[rr].x, acc[rr].y);
        *reinterpret_cast<float2*>(&out[obase + 2]) = make_float2(acc[rr].z, acc[rr].w);
      } else {
        float v[4] = {acc[rr].x, acc[rr].y, acc[rr].z, acc[rr].w};
        #pragma unroll
        for (int jj = 0; jj < 4; ++jj)
          if (j0 + jj < N) out[obase + jj] = v[jj];
      }
    }
  }
}

// ---------------------------------------------------------------------------
// R0: fused scan H=16 (4 rows per single wave) + projection to HN=32.
// ---------------------------------------------------------------------------
__global__ __launch_bounds__(64) REC_ATTR
void fused_rec16(const float* __restrict__ xw, const float* __restrict__ U,
                 const float* __restrict__ Wn, const float* __restrict__ bn,
                 float* __restrict__ xwn)
{
  constexpr int H = 16, ROWS = 4, HN = 32, PF = 8;
  const int tid = threadIdx.x;
  const int r = tid >> 4, j = tid & 15;
  const int c = tid & 31, pr = tid >> 5;
  __shared__ __align__(16) float hlds[ROWS][H];
  for (int i = tid; i < ROWS * H; i += 64) reinterpret_cast<float*>(hlds)[i] = 0.0f;
  __syncthreads();

  float u[H], w[H];
  #pragma unroll
  for (int kk = 0; kk < H; ++kk) {
    u[kk] = U[kk * H + j];
    w[kk] = Wn[kk * HN + c];
    asm volatile("" : "+v"(u[kk]), "+v"(w[kk]));
  }
  const float bc = bn[c];

  const float* xwrow = xw + ((size_t)(blockIdx.x * ROWS + r) * TT) * H + j;
  float* o0 = xwn + ((size_t)(blockIdx.x * ROWS + 2 * pr + 0) * TT) * HN + c;
  float* o1 = xwn + ((size_t)(blockIdx.x * ROWS + 2 * pr + 1) * TT) * HN + c;

  float pf[PF];
  #pragma unroll
  for (int d = 0; d < PF; ++d) pf[d] = xwrow[(size_t)d * H];

  for (int t = 0; t < TT; t += PF) {
    #pragma unroll
    for (int d = 0; d < PF; ++d) {
      float xv = pf[d];
      int tn = t + d + PF;
      tn = (tn < TT) ? tn : (TT - 1);
      pf[d] = xwrow[(size_t)tn * H];

      const float* hb = &hlds[r][0];
      float a0 = xv, a1 = 0.0f, a2 = 0.0f, a3 = 0.0f;
      #pragma unroll
      for (int k4 = 0; k4 < H / 4; ++k4) {
        float4 h4 = *reinterpret_cast<const float4*>(hb + 4 * k4);
        a0 = fmaf(h4.x, u[4 * k4 + 0], a0);
        a1 = fmaf(h4.y, u[4 * k4 + 1], a1);
        a2 = fmaf(h4.z, u[4 * k4 + 2], a2);
        a3 = fmaf(h4.w, u[4 * k4 + 3], a3);
      }
      float hn = tanh_fast((a0 + a1) + (a2 + a3));
      hlds[r][j] = hn;  // in-order DS within the wave

      // projection: uses h_t of rows 2pr, 2pr+1 (just written)
      const float* h0b = &hlds[2 * pr + 0][0];
      const float* h1b = &hlds[2 * pr + 1][0];
      float s0 = bc, s1 = bc, s2 = 0.0f, s3 = 0.0f;
      #pragma unroll
      for (int k4 = 0; k4 < H / 4; ++k4) {
        float4 ha = *reinterpret_cast<const float4*>(h0b + 4 * k4);
        float4 hc = *reinterpret_cast<const float4*>(h1b + 4 * k4);
        s0 = fmaf(ha.x, w[4 * k4 + 0], s0);
        s2 = fmaf(ha.y, w[4 * k4 + 1], s2);
        s0 = fmaf(ha.z, w[4 * k4 + 2], s0);
        s2 = fmaf(ha.w, w[4 * k4 + 3], s2);
        s1 = fmaf(hc.x, w[4 * k4 + 0], s1);
        s3 = fmaf(hc.y, w[4 * k4 + 1], s3);
        s1 = fmaf(hc.z, w[4 * k4 + 2], s1);
        s3 = fmaf(hc.w, w[4 * k4 + 3], s3);
      }
      o0[(size_t)(t + d) * HN] = s0 + s2;  // fire-and-forget
      o1[(size_t)(t + d) * HN] = s1 + s3;
    }
  }
}

// ---------------------------------------------------------------------------
// R1: fused scan H=32 (2 rows per single wave) + projection to HN=64.
// ---------------------------------------------------------------------------
__global__ __launch_bounds__(64) REC_ATTR
void fused_rec32(const float* __restrict__ xw, const float* __restrict__ U,
                 const float* __restrict__ Wn, const float* __restrict__ bn,
                 float* __restrict__ xwn)
{
  constexpr int H = 32, ROWS = 2, HN = 64, PF = 8;
  const int tid = threadIdx.x;
  const int r = tid >> 5, j = tid & 31;
  const int c = tid;
  __shared__ __align__(16) float hlds[ROWS][H];
  for (int i = tid; i < ROWS * H; i += 64) reinterpret_cast<float*>(hlds)[i] = 0.0f;
  __syncthreads();

  float u[H], w[H];
  #pragma unroll
  for (int kk = 0; kk < H; ++kk) {
    u[kk] = U[kk * H + j];
    w[kk] = Wn[kk * HN + c];
    asm volatile("" : "+v"(u[kk]), "+v"(w[kk]));
  }
  const float bc = bn[c];

  const float* xwrow = xw + ((size_t)(blockIdx.x * ROWS + r) * TT) * H + j;
  float* o0 = xwn + ((size_t)(blockIdx.x * ROWS + 0) * TT) * HN + c;
  float* o1 = xwn + ((size_t)(blockIdx.x * ROWS + 1) * TT) * HN + c;

  float pf[PF];
  #pragma unroll
  for (int d = 0; d < PF; ++d) pf[d] = xwrow[(size_t)d * H];

  for (int t = 0; t < TT; t += PF) {
    #pragma unroll
    for (int d = 0; d < PF; ++d) {
      float xv = pf[d];
      int tn = t + d + PF;
      tn = (tn < TT) ? tn : (TT - 1);
      pf[d] = xwrow[(size_t)tn * H];

      const float* hb = &hlds[r][0];
      float a0 = xv, a1 = 0.0f, a2 = 0.0f, a3 = 0.0f;
      #pragma unroll
      for (int k4 = 0; k4 < H / 4; ++k4) {
        float4 h4 = *reinterpret_cast<const float4*>(hb + 4 * k4);
        a0 = fmaf(h4.x, u[4 * k4 + 0], a0);
        a1 = fmaf(h4.y, u[4 * k4 + 1], a1);
        a2 = fmaf(h4.z, u[4 * k4 + 2], a2);
        a3 = fmaf(h4.w, u[4 * k4 + 3], a3);
      }
      float hn = tanh_fast((a0 + a1) + (a2 + a3));
      hlds[r][j] = hn;

      const float* h0b = &hlds[0][0];
      const float* h1b = &hlds[1][0];
      float s0 = bc, s1 = bc, s2 = 0.0f, s3 = 0.0f;
      #pragma unroll
      for (int k4 = 0; k4 < H / 4; ++k4) {
        float4 ha = *reinterpret_cast<const float4*>(h0b + 4 * k4);
        float4 hc = *reinterpret_cast<const float4*>(h1b + 4 * k4);
        s0 = fmaf(ha.x, w[4 * k4 + 0], s0);
        s2 = fmaf(ha.y, w[4 * k4 + 1], s2);
        s0 = fmaf(ha.z, w[4 * k4 + 2], s0);
        s2 = fmaf(ha.w, w[4 * k4 + 3], s2);
        s1 = fmaf(hc.x, w[4 * k4 + 0], s1);
        s3 = fmaf(hc.y, w[4 * k4 + 1], s3);
        s1 = fmaf(hc.z, w[4 * k4 + 2], s1);
        s3 = fmaf(hc.w, w[4 * k4 + 3], s3);
      }
      o0[(size_t)(t + d) * HN] = s0 + s2;
      o1[(size_t)(t + d) * HN] = s1 + s3;
    }
  }
}

// ---------------------------------------------------------------------------
// rec64: plain scan H=64, 1 row per single wave.  Outputs h sequence.
// ---------------------------------------------------------------------------
__global__ __launch_bounds__(64) REC_ATTR
void rec64_kernel(const float* __restrict__ xw, const float* __restrict__ U,
                  float* __restrict__ hseq)
{
  constexpr int H = 64, PF = 8;
  const int tid = threadIdx.x;
  const int row = blockIdx.x;

  __shared__ __align__(16) float hlds[H];
  hlds[tid] = 0.0f;
  __syncthreads();

  float u[H];
  #pragma unroll
  for (int kk = 0; kk < H; ++kk) {
    u[kk] = U[kk * H + tid];
    asm volatile("" : "+v"(u[kk]));
  }

  const float* xwrow = xw + ((size_t)row * TT) * H + tid;
  float* hout = hseq + ((size_t)row * TT) * H + tid;

  float pf[PF];
  #pragma unroll
  for (int d = 0; d < PF; ++d) pf[d] = xwrow[(size_t)d * H];

  for (int t = 0; t < TT; t += PF) {
    #pragma unroll
    for (int d = 0; d < PF; ++d) {
      float xv = pf[d];
      int tn = t + d + PF;
      tn = (tn < TT) ? tn : (TT - 1);
      pf[d] = xwrow[(size_t)tn * H];

      float a0 = xv, a1 = 0.0f, a2 = 0.0f, a3 = 0.0f;
      #pragma unroll
      for (int k4 = 0; k4 < H / 4; ++k4) {
        float4 h4 = *reinterpret_cast<const float4*>(&hlds[4 * k4]);
        a0 = fmaf(h4.x, u[4 * k4 + 0], a0);
        a1 = fmaf(h4.y, u[4 * k4 + 1], a1);
        a2 = fmaf(h4.z, u[4 * k4 + 2], a2);
        a3 = fmaf(h4.w, u[4 * k4 + 3], a3);
      }
      float hn = tanh_fast((a0 + a1) + (a2 + a3));
      hlds[tid] = hn;
      hout[(size_t)(t + d) * H] = hn;
    }
  }
}

// ---------------------------------------------------------------------------
// rec70: 2-wave (128-thread) scan H=70, one column per lane (70 active).
// h double-buffered in LDS, one lgkmcnt+s_barrier per step.  Fused dense+softmax.
// ---------------------------------------------------------------------------
__global__ __launch_bounds__(128) REC_ATTR
void rec70_kernel(const float* __restrict__ xw, const float* __restrict__ U,
                  const float* __restrict__ Wd, const float* __restrict__ bd,
                  float* __restrict__ outp)
{
  constexpr int H = 70, HP = 72, PF = 8;
  const int tid = threadIdx.x;
  const int row = blockIdx.x;
  const bool act = tid < H;
  const int j = act ? tid : 0;

  __shared__ __align__(16) float hbuf[2][HP];
  for (int i = tid; i < 2 * HP; i += 128) reinterpret_cast<float*>(hbuf)[i] = 0.0f;
  __syncthreads();

  float u[HP];
  #pragma unroll
  for (int kk = 0; kk < HP; ++kk) {
    u[kk] = (kk < H && act) ? U[kk * H + j] : 0.0f;
    asm volatile("" : "+v"(u[kk]));
  }

  const float* xwrow = xw + ((size_t)row * TT) * H + j;
  float pf[PF];
  #pragma unroll
  for (int d = 0; d < PF; ++d) pf[d] = xwrow[(size_t)d * H];

  for (int t = 0; t < TT; t += PF) {
    #pragma unroll
    for (int d = 0; d < PF; ++d) {
      float xv = pf[d];
      int tn = t + d + PF;
      tn = (tn < TT) ? tn : (TT - 1);
      pf[d] = xwrow[(size_t)tn * H];

      const float* hb = &hbuf[(t + d) & 1][0];
      float a0 = xv, a1 = 0.0f, a2 = 0.0f, a3 = 0.0f;
      #pragma unroll
      for (int k4 = 0; k4 < HP / 4; ++k4) {
        float4 h4 = *reinterpret_cast<const float4*>(hb + 4 * k4);
        a0 = fmaf(h4.x, u[4 * k4 + 0], a0);
        a1 = fmaf(h4.y, u[4 * k4 + 1], a1);
        a2 = fmaf(h4.z, u[4 * k4 + 2], a2);
        a3 = fmaf(h4.w, u[4 * k4 + 3], a3);
      }
      float hn = tanh_fast((a0 + a1) + (a2 + a3));
      if (act) hbuf[((t + d) & 1) ^ 1][j] = hn;  // write next-state buffer
      LDS_BARRIER();
    }
  }

  // TT even -> final h is in hbuf[0].  Dense (70->5) + softmax in wave 0.
  float l = 0.0f;
  if (tid < 5) {
    l = bd[tid];
    #pragma unroll
    for (int kk = 0; kk < H; ++kk)
      l = fmaf(hbuf[0][kk], Wd[kk * 5 + tid], l);
  }
  float l0 = __shfl(l, 0), l1 = __shfl(l, 1), l2 = __shfl(l, 2),
        l3 = __shfl(l, 3), l4 = __shfl(l, 4);
  float m = fmaxf(fmaxf(fmaxf(l0, l1), fmaxf(l2, l3)), l4);
  float s = __expf(l0 - m) + __expf(l1 - m) + __expf(l2 - m) +
            __expf(l3 - m) + __expf(l4 - m);
  if (tid < 5)
    outp[(size_t)row * 5 + tid] = __expf(l - m) / s;
}

extern "C" void kernel_launch(void* const* d_in, const int* in_sizes, int n_in,
                              void* d_out, int out_size, void* d_ws, size_t ws_size,
                              hipStream_t stream)
{
  const float* x  = (const float*)d_in[0];
  const float* W0 = (const float*)d_in[1];
  const float* U0 = (const float*)d_in[2];
  const float* b0 = (const float*)d_in[3];
  const float* W1 = (const float*)d_in[4];
  const float* U1 = (const float*)d_in[5];
  const float* b1 = (const float*)d_in[6];
  const float* W2 = (const float*)d_in[7];
  const float* U2 = (const float*)d_in[8];
  const float* b2 = (const float*)d_in[9];
  const float* W3 = (const float*)d_in[10];
  const float* U3 = (const float*)d_in[11];
  const float* b3 = (const float*)d_in[12];
  const float* Wd = (const float*)d_in[13];
  const float* bd = (const float*)d_in[14];
  float* outp = (float*)d_out;

  // A: xw0 [M,16] -> xw2 [M,64] -> xw3 [M,70] (73,400,320 B)
  // Bv: xw1 [M,32] -> h2 [M,64]               (67,108,864 B)
  float* A  = (float*)d_ws;
  float* Bv = (float*)((char*)d_ws + 73400320);

  const int M = M_TOTAL;

  // xw0 = x @ W0 + b0
  proj_kernel<78, 16, 4><<<M / 256, 256, 0, stream>>>(x, W0, b0, A, M);
  // scan L0 + fused xw1 = h0 @ W1 + b1
  fused_rec16<<<BB / 4, 64, 0, stream>>>(A, U0, W1, b1, Bv);
  // scan L1 + fused xw2 = h1 @ W2 + b2
  fused_rec32<<<BB / 2, 64, 0, stream>>>(Bv, U1, W2, b2, A);
  // scan L2 -> h2 sequence
  rec64_kernel<<<BB, 64, 0, stream>>>(A, U2, Bv);
  // xw3 = h2 @ W3 + b3
  proj_kernel<64, 70, 18><<<(M + 55) / 56, 256, 0, stream>>>(Bv, W3, b3, A, M);
  // scan L3 (2-wave) + dense + softmax
  rec70_kernel<<<BB, 128, 0, stream>>>(A, U3, Wd, bd, outp);
}

// Round 7
// 979.863 us; speedup vs baseline: 1.1756x; 1.0106x over previous
//
#include <hip/hip_runtime.h>
#include <cstddef>
#include <cstdint>

// Stacked SimpleRNN, fp32.  B=512, T=512, F=78, hiddens 16/32/64/70, dense->5+softmax.
//
// Round-7 theory: per-step scattered VMEM (64-cache-line gather loads + scattered
// stores on the serial chain) is the ~900cyc/step hidden wall.  Fix: chunked LDS
// slab staging (CH=16 steps) -- coalesced float4 slab loads double-buffered in LDS,
// per-step xw from stride-1 LDS reads, outputs staged in LDS and flushed coalesced
// once per chunk.  ZERO vmem instructions inside a step.
#define REC_ATTR __attribute__((amdgpu_waves_per_eu(1, 1)))

#define BB 512
#define TT 512
#define M_TOTAL (BB * TT)

// LDS-visibility sync WITHOUT a vmcnt drain (keeps global traffic in flight).
#define LDS_BARRIER() asm volatile("s_waitcnt lgkmcnt(0)\n\ts_barrier" ::: "memory")

__device__ __forceinline__ float tanh_fast(float x) {
  float ax = fabsf(x);
  float e = __expf(ax + ax);
  float r = 1.0f - 2.0f / (e + 1.0f);
  return (x >= 0.0f) ? r : -r;
}

__device__ __forceinline__ void fma4(float4& a, float s, const float4 w) {
  a.x = fmaf(s, w.x, a.x);
  a.y = fmaf(s, w.y, a.y);
  a.z = fmaf(s, w.z, a.z);
  a.w = fmaf(s, w.w, a.w);
}

// ---------------------------------------------------------------------------
// proj: out[M,N] = in[M,K] @ W[K,N] + b.  256 threads; 4x4 tile per thread.
// ---------------------------------------------------------------------------
template<int K, int N, int CG>
__global__ __launch_bounds__(256)
void proj_kernel(const float* __restrict__ in, const float* __restrict__ W,
                 const float* __restrict__ bias, float* __restrict__ out, int M)
{
  constexpr int NP = CG * 4;
  constexpr int RG = 256 / CG;
  __shared__ __align__(16) float wlds[K][NP];
  __shared__ __align__(16) float blds[NP];
  const int tid = threadIdx.x;
  for (int idx = tid; idx < K * NP; idx += 256) {
    int k = idx / NP, jj = idx - k * NP;
    wlds[k][jj] = (jj < N) ? W[k * N + jj] : 0.0f;
  }
  if (tid < NP) blds[tid] = (tid < N) ? bias[tid] : 0.0f;
  __syncthreads();

  const int c = tid % CG;
  const int rg = tid / CG;
  if (rg >= RG) return;
  const int j0 = c * 4;
  const long row0 = (long)blockIdx.x * (RG * 4) + (long)rg * 4;

  float4 b4 = *reinterpret_cast<const float4*>(&blds[j0]);
  float4 acc[4] = {b4, b4, b4, b4};
  const float* inp[4];
  bool rv[4];
  #pragma unroll
  for (int rr = 0; rr < 4; ++rr) {
    long rowi = row0 + rr;
    rv[rr] = rowi < M;
    inp[rr] = in + (rv[rr] ? rowi : 0) * (long)K;
  }

  int k = 0;
  for (; k + 4 <= K; k += 4) {
    float4 w0 = *reinterpret_cast<const float4*>(&wlds[k + 0][j0]);
    float4 w1 = *reinterpret_cast<const float4*>(&wlds[k + 1][j0]);
    float4 w2 = *reinterpret_cast<const float4*>(&wlds[k + 2][j0]);
    float4 w3 = *reinterpret_cast<const float4*>(&wlds[k + 3][j0]);
    #pragma unroll
    for (int rr = 0; rr < 4; ++rr) {
      float2 i0 = *reinterpret_cast<const float2*>(inp[rr] + k);
      float2 i1 = *reinterpret_cast<const float2*>(inp[rr] + k + 2);
      fma4(acc[rr], i0.x, w0);
      fma4(acc[rr], i0.y, w1);
      fma4(acc[rr], i1.x, w2);
      fma4(acc[rr], i1.y, w3);
    }
  }
  for (; k < K; ++k) {
    float4 w0 = *reinterpret_cast<const float4*>(&wlds[k][j0]);
    #pragma unroll
    for (int rr = 0; rr < 4; ++rr) fma4(acc[rr], inp[rr][k], w0);
  }

  #pragma unroll
  for (int rr = 0; rr < 4; ++rr) {
    if (!rv[rr]) continue;
    long obase = (row0 + rr) * (long)N + j0;
    if constexpr ((N % 4) == 0) {
      *reinterpret_cast<float4*>(&out[obase]) = acc[rr];
    } else {
      if (j0 + 4 <= N) {
        *reinterpret_cast<float2*>(&out[obase]) = make_float2(acc[rr].x, acc[rr].y);
        *reinterpret_cast<float2*>(&out[obase + 2]) = make_float2(acc[rr].z, acc[rr].w);
      } else {
        float v[4] = {acc[rr].x, acc[rr].y, acc[rr].z, acc[rr].w};
        #pragma unroll
        for (int jj = 0; jj < 4; ++jj)
          if (j0 + jj < N) out[obase + jj] = v[jj];
      }
    }
  }
}

// ---------------------------------------------------------------------------
// R0: fused scan H=16 (4 rows, 1 wave) + proj to HN=32.  Slab-staged I/O.
// ---------------------------------------------------------------------------
__global__ __launch_bounds__(64) REC_ATTR
void fused_rec16(const float* __restrict__ xw, const float* __restrict__ U,
                 const float* __restrict__ Wn, const float* __restrict__ bn,
                 float* __restrict__ xwn)
{
  constexpr int H = 16, ROWS = 4, HN = 32, CH = 16, NCH = TT / CH;
  constexpr int XINR = 264;  // padded row stride (floats): 2 lanes/bank on reads
  const int tid = threadIdx.x;
  const int r = tid >> 4, j = tid & 15;
  const int c = tid & 31, pr = tid >> 5;
  __shared__ __align__(16) float xin[2][ROWS * XINR];
  __shared__ __align__(16) float xout[ROWS * CH * HN];  // [r][s][c]
  __shared__ __align__(16) float hlds[ROWS][H];

  float u[H], w[H];
  #pragma unroll
  for (int kk = 0; kk < H; ++kk) {
    u[kk] = U[kk * H + j];
    w[kk] = Wn[kk * HN + c];
    asm volatile("" : "+v"(u[kk]), "+v"(w[kk]));
  }
  const float bc = bn[c];

  const int row0 = blockIdx.x * ROWS;
  const float* gin[ROWS];
  float* gout[ROWS];
  #pragma unroll
  for (int rr = 0; rr < ROWS; ++rr) {
    gin[rr] = xw + ((size_t)(row0 + rr) * TT) * H;
    gout[rr] = xwn + ((size_t)(row0 + rr) * TT) * HN;
  }
  // zero h, stage chunk 0 (single wave: in-order DS, no barrier needed)
  for (int i = tid; i < ROWS * H; i += 64) reinterpret_cast<float*>(hlds)[i] = 0.0f;
  #pragma unroll
  for (int rr = 0; rr < ROWS; ++rr) {
    float4 v = reinterpret_cast<const float4*>(gin[rr])[tid];  // 256 floats/row
    *reinterpret_cast<float4*>(&xin[0][rr * XINR + tid * 4]) = v;
  }

  for (int ch = 0; ch < NCH; ++ch) {
    const int buf = ch & 1, nb = buf ^ 1;
    const int ch1 = (ch + 1 < NCH) ? ch + 1 : ch;
    float4 nv[ROWS];
    #pragma unroll
    for (int rr = 0; rr < ROWS; ++rr)
      nv[rr] = reinterpret_cast<const float4*>(gin[rr] + (size_t)ch1 * CH * H)[tid];

    #pragma unroll
    for (int s = 0; s < CH; ++s) {
      float xv = xin[buf][r * XINR + s * H + j];
      float a0 = xv, a1 = 0.0f, a2 = 0.0f, a3 = 0.0f;
      const float* hb = &hlds[r][0];
      #pragma unroll
      for (int k4 = 0; k4 < H / 4; ++k4) {
        float4 h4 = *reinterpret_cast<const float4*>(hb + 4 * k4);
        a0 = fmaf(h4.x, u[4 * k4 + 0], a0);
        a1 = fmaf(h4.y, u[4 * k4 + 1], a1);
        a2 = fmaf(h4.z, u[4 * k4 + 2], a2);
        a3 = fmaf(h4.w, u[4 * k4 + 3], a3);
      }
      float hn = tanh_fast((a0 + a1) + (a2 + a3));
      hlds[r][j] = hn;
      const float* h0b = &hlds[2 * pr + 0][0];
      const float* h1b = &hlds[2 * pr + 1][0];
      float s0 = bc, s1 = bc, s2 = 0.0f, s3 = 0.0f;
      #pragma unroll
      for (int k4 = 0; k4 < H / 4; ++k4) {
        float4 ha = *reinterpret_cast<const float4*>(h0b + 4 * k4);
        float4 hc = *reinterpret_cast<const float4*>(h1b + 4 * k4);
        s0 = fmaf(ha.x, w[4 * k4 + 0], s0);
        s2 = fmaf(ha.y, w[4 * k4 + 1], s2);
        s0 = fmaf(ha.z, w[4 * k4 + 2], s0);
        s2 = fmaf(ha.w, w[4 * k4 + 3], s2);
        s1 = fmaf(hc.x, w[4 * k4 + 0], s1);
        s3 = fmaf(hc.y, w[4 * k4 + 1], s3);
        s1 = fmaf(hc.z, w[4 * k4 + 2], s1);
        s3 = fmaf(hc.w, w[4 * k4 + 3], s3);
      }
      xout[(2 * pr + 0) * (CH * HN) + s * HN + c] = s0 + s2;
      xout[(2 * pr + 1) * (CH * HN) + s * HN + c] = s1 + s3;
    }
    // flush this chunk's outputs, coalesced
    #pragma unroll
    for (int rr = 0; rr < ROWS; ++rr) {
      float* gslab = gout[rr] + (size_t)(ch * CH) * HN;
      #pragma unroll
      for (int q = 0; q < 2; ++q) {
        float4 f = reinterpret_cast<const float4*>(&xout[rr * (CH * HN)])[q * 64 + tid];
        reinterpret_cast<float4*>(gslab)[q * 64 + tid] = f;
      }
    }
    // stage next chunk (vmcnt wait lands ~16 steps after issue)
    #pragma unroll
    for (int rr = 0; rr < ROWS; ++rr)
      *reinterpret_cast<float4*>(&xin[nb][rr * XINR + tid * 4]) = nv[rr];
  }
}

// ---------------------------------------------------------------------------
// R1: fused scan H=32 (2 rows, 1 wave) + proj to HN=64.  Slab-staged I/O.
// ---------------------------------------------------------------------------
__global__ __launch_bounds__(64) REC_ATTR
void fused_rec32(const float* __restrict__ xw, const float* __restrict__ U,
                 const float* __restrict__ Wn, const float* __restrict__ bn,
                 float* __restrict__ xwn)
{
  constexpr int H = 32, ROWS = 2, HN = 64, CH = 16, NCH = TT / CH;
  constexpr int XINR = 520;  // padded row stride
  const int tid = threadIdx.x;
  const int r = tid >> 5, j = tid & 31;
  const int c = tid;
  __shared__ __align__(16) float xin[2][ROWS * XINR];
  __shared__ __align__(16) float xout[ROWS * CH * HN];  // [r][s][c]
  __shared__ __align__(16) float hlds[ROWS][H];

  float u[H], w[H];
  #pragma unroll
  for (int kk = 0; kk < H; ++kk) {
    u[kk] = U[kk * H + j];
    w[kk] = Wn[kk * HN + c];
    asm volatile("" : "+v"(u[kk]), "+v"(w[kk]));
  }
  const float bc = bn[c];

  const int row0 = blockIdx.x * ROWS;
  const float* gin[ROWS];
  float* gout[ROWS];
  #pragma unroll
  for (int rr = 0; rr < ROWS; ++rr) {
    gin[rr] = xw + ((size_t)(row0 + rr) * TT) * H;
    gout[rr] = xwn + ((size_t)(row0 + rr) * TT) * HN;
  }
  for (int i = tid; i < ROWS * H; i += 64) reinterpret_cast<float*>(hlds)[i] = 0.0f;
  #pragma unroll
  for (int rr = 0; rr < ROWS; ++rr)
    #pragma unroll
    for (int q = 0; q < 2; ++q) {
      float4 v = reinterpret_cast<const float4*>(gin[rr])[q * 64 + tid];  // 512 floats/row
      *reinterpret_cast<float4*>(&xin[0][rr * XINR + (q * 64 + tid) * 4]) = v;
    }

  for (int ch = 0; ch < NCH; ++ch) {
    const int buf = ch & 1, nb = buf ^ 1;
    const int ch1 = (ch + 1 < NCH) ? ch + 1 : ch;
    float4 nv[ROWS][2];
    #pragma unroll
    for (int rr = 0; rr < ROWS; ++rr)
      #pragma unroll
      for (int q = 0; q < 2; ++q)
        nv[rr][q] = reinterpret_cast<const float4*>(gin[rr] + (size_t)ch1 * CH * H)[q * 64 + tid];

    #pragma unroll
    for (int s = 0; s < CH; ++s) {
      float xv = xin[buf][r * XINR + s * H + j];
      float a0 = xv, a1 = 0.0f, a2 = 0.0f, a3 = 0.0f;
      const float* hb = &hlds[r][0];
      #pragma unroll
      for (int k4 = 0; k4 < H / 4; ++k4) {
        float4 h4 = *reinterpret_cast<const float4*>(hb + 4 * k4);
        a0 = fmaf(h4.x, u[4 * k4 + 0], a0);
        a1 = fmaf(h4.y, u[4 * k4 + 1], a1);
        a2 = fmaf(h4.z, u[4 * k4 + 2], a2);
        a3 = fmaf(h4.w, u[4 * k4 + 3], a3);
      }
      float hn = tanh_fast((a0 + a1) + (a2 + a3));
      hlds[r][j] = hn;
      const float* h0b = &hlds[0][0];
      const float* h1b = &hlds[1][0];
      float s0 = bc, s1 = bc, s2 = 0.0f, s3 = 0.0f;
      #pragma unroll
      for (int k4 = 0; k4 < H / 4; ++k4) {
        float4 ha = *reinterpret_cast<const float4*>(h0b + 4 * k4);
        float4 hc = *reinterpret_cast<const float4*>(h1b + 4 * k4);
        s0 = fmaf(ha.x, w[4 * k4 + 0], s0);
        s2 = fmaf(ha.y, w[4 * k4 + 1], s2);
        s0 = fmaf(ha.z, w[4 * k4 + 2], s0);
        s2 = fmaf(ha.w, w[4 * k4 + 3], s2);
        s1 = fmaf(hc.x, w[4 * k4 + 0], s1);
        s3 = fmaf(hc.y, w[4 * k4 + 1], s3);
        s1 = fmaf(hc.z, w[4 * k4 + 2], s1);
        s3 = fmaf(hc.w, w[4 * k4 + 3], s3);
      }
      xout[0 * (CH * HN) + s * HN + c] = s0 + s2;
      xout[1 * (CH * HN) + s * HN + c] = s1 + s3;
    }
    #pragma unroll
    for (int rr = 0; rr < ROWS; ++rr) {
      float* gslab = gout[rr] + (size_t)(ch * CH) * HN;
      #pragma unroll
      for (int q = 0; q < 4; ++q) {
        float4 f = reinterpret_cast<const float4*>(&xout[rr * (CH * HN)])[q * 64 + tid];
        reinterpret_cast<float4*>(gslab)[q * 64 + tid] = f;
      }
    }
    #pragma unroll
    for (int rr = 0; rr < ROWS; ++rr)
      #pragma unroll
      for (int q = 0; q < 2; ++q)
        *reinterpret_cast<float4*>(&xin[nb][rr * XINR + (q * 64 + tid) * 4]) = nv[rr][q];
  }
}

// ---------------------------------------------------------------------------
// rec64: scan H=64, 1 row, 1 wave.  Slab-staged input AND h-sequence output.
// ---------------------------------------------------------------------------
__global__ __launch_bounds__(64) REC_ATTR
void rec64_kernel(const float* __restrict__ xw, const float* __restrict__ U,
                  float* __restrict__ hseq)
{
  constexpr int H = 64, CH = 16, NCH = TT / CH;
  const int tid = threadIdx.x;
  const int row = blockIdx.x;
  __shared__ __align__(16) float xin[2][CH * H];
  __shared__ __align__(16) float xout[CH * H];
  __shared__ __align__(16) float hlds[H];

  float u[H];
  #pragma unroll
  for (int kk = 0; kk < H; ++kk) {
    u[kk] = U[kk * H + tid];
    asm volatile("" : "+v"(u[kk]));
  }
  const float* gin = xw + ((size_t)row * TT) * H;
  float* gout = hseq + ((size_t)row * TT) * H;

  hlds[tid] = 0.0f;
  #pragma unroll
  for (int q = 0; q < 4; ++q) {
    float4 v = reinterpret_cast<const float4*>(gin)[q * 64 + tid];  // 1024 floats
    *reinterpret_cast<float4*>(&xin[0][(q * 64 + tid) * 4]) = v;
  }

  for (int ch = 0; ch < NCH; ++ch) {
    const int buf = ch & 1, nb = buf ^ 1;
    const int ch1 = (ch + 1 < NCH) ? ch + 1 : ch;
    float4 nv[4];
    #pragma unroll
    for (int q = 0; q < 4; ++q)
      nv[q] = reinterpret_cast<const float4*>(gin + (size_t)ch1 * CH * H)[q * 64 + tid];

    #pragma unroll
    for (int s = 0; s < CH; ++s) {
      float xv = xin[buf][s * H + tid];
      float a0 = xv, a1 = 0.0f, a2 = 0.0f, a3 = 0.0f;
      #pragma unroll
      for (int k4 = 0; k4 < H / 4; ++k4) {
        float4 h4 = *reinterpret_cast<const float4*>(&hlds[4 * k4]);
        a0 = fmaf(h4.x, u[4 * k4 + 0], a0);
        a1 = fmaf(h4.y, u[4 * k4 + 1], a1);
        a2 = fmaf(h4.z, u[4 * k4 + 2], a2);
        a3 = fmaf(h4.w, u[4 * k4 + 3], a3);
      }
      float hn = tanh_fast((a0 + a1) + (a2 + a3));
      hlds[tid] = hn;
      xout[s * H + tid] = hn;
    }
    float* gslab = gout + (size_t)(ch * CH) * H;
    #pragma unroll
    for (int q = 0; q < 4; ++q) {
      float4 f = reinterpret_cast<const float4*>(xout)[q * 64 + tid];
      reinterpret_cast<float4*>(gslab)[q * 64 + tid] = f;
    }
    #pragma unroll
    for (int q = 0; q < 4; ++q)
      *reinterpret_cast<float4*>(&xin[nb][(q * 64 + tid) * 4]) = nv[q];
  }
}

// ---------------------------------------------------------------------------
// rec70: 2-wave scan H=70 (one column/lane), h double-buffered in LDS, one
// lgkmcnt+s_barrier per step.  Slab-staged xw input (scalar-guarded loads).
// Fused dense(70->5) + softmax.
// ---------------------------------------------------------------------------
__global__ __launch_bounds__(128) REC_ATTR
void rec70_kernel(const float* __restrict__ xw, const float* __restrict__ U,
                  const float* __restrict__ Wd, const float* __restrict__ bd,
                  float* __restrict__ outp)
{
  constexpr int H = 70, HP = 72, CH = 16, NCH = TT / CH, SLAB = CH * H;  // 1120
  constexpr int NL = 9;  // ceil(1120/128)
  const int tid = threadIdx.x;
  const int row = blockIdx.x;
  const bool act = tid < H;
  const int j = act ? tid : 0;

  __shared__ __align__(16) float xin[2][1152];
  __shared__ __align__(16) float hbuf[2][HP];

  float u[HP];
  #pragma unroll
  for (int kk = 0; kk < HP; ++kk) {
    u[kk] = (kk < H && act) ? U[kk * H + j] : 0.0f;
    asm volatile("" : "+v"(u[kk]));
  }

  const float* gin = xw + ((size_t)row * TT) * H;
  for (int i = tid; i < 2 * HP; i += 128) reinterpret_cast<float*>(hbuf)[i] = 0.0f;
  #pragma unroll
  for (int q = 0; q < NL; ++q) {
    int idx = q * 128 + tid;
    xin[0][idx] = (idx < SLAB) ? gin[idx] : 0.0f;
  }
  __syncthreads();  // once, pre-loop

  for (int ch = 0; ch < NCH; ++ch) {
    const int buf = ch & 1, nb = buf ^ 1;
    const int ch1 = (ch + 1 < NCH) ? ch + 1 : ch;
    const float* gslab = gin + (size_t)ch1 * SLAB;
    float nv[NL];
    #pragma unroll
    for (int q = 0; q < NL; ++q) {
      int idx = q * 128 + tid;
      nv[q] = (idx < SLAB) ? gslab[idx] : 0.0f;
    }

    #pragma unroll
    for (int s = 0; s < CH; ++s) {
      float xv = xin[buf][s * H + j];
      const float* hb = &hbuf[s & 1][0];
      float a0 = xv, a1 = 0.0f, a2 = 0.0f, a3 = 0.0f;
      #pragma unroll
      for (int k4 = 0; k4 < HP / 4; ++k4) {
        float4 h4 = *reinterpret_cast<const float4*>(hb + 4 * k4);
        a0 = fmaf(h4.x, u[4 * k4 + 0], a0);
        a1 = fmaf(h4.y, u[4 * k4 + 1], a1);
        a2 = fmaf(h4.z, u[4 * k4 + 2], a2);
        a3 = fmaf(h4.w, u[4 * k4 + 3], a3);
      }
      float hn = tanh_fast((a0 + a1) + (a2 + a3));
      if (act) hbuf[(s & 1) ^ 1][j] = hn;
      if (s == CH - 1) {  // stage next slab just before the chunk-boundary barrier
        #pragma unroll
        for (int q = 0; q < NL; ++q) xin[nb][q * 128 + tid] = nv[q];
      }
      LDS_BARRIER();
    }
  }

  // final h is in hbuf[0].  Dense (70->5) + softmax.
  float l = 0.0f;
  if (tid < 5) {
    l = bd[tid];
    #pragma unroll
    for (int kk = 0; kk < H; ++kk)
      l = fmaf(hbuf[0][kk], Wd[kk * 5 + tid], l);
  }
  float l0 = __shfl(l, 0), l1 = __shfl(l, 1), l2 = __shfl(l, 2),
        l3 = __shfl(l, 3), l4 = __shfl(l, 4);
  float m = fmaxf(fmaxf(fmaxf(l0, l1), fmaxf(l2, l3)), l4);
  float s = __expf(l0 - m) + __expf(l1 - m) + __expf(l2 - m) +
            __expf(l3 - m) + __expf(l4 - m);
  if (tid < 5)
    outp[(size_t)row * 5 + tid] = __expf(l - m) / s;
}

extern "C" void kernel_launch(void* const* d_in, const int* in_sizes, int n_in,
                              void* d_out, int out_size, void* d_ws, size_t ws_size,
                              hipStream_t stream)
{
  const float* x  = (const float*)d_in[0];
  const float* W0 = (const float*)d_in[1];
  const float* U0 = (const float*)d_in[2];
  const float* b0 = (const float*)d_in[3];
  const float* W1 = (const float*)d_in[4];
  const float* U1 = (const float*)d_in[5];
  const float* b1 = (const float*)d_in[6];
  const float* W2 = (const float*)d_in[7];
  const float* U2 = (const float*)d_in[8];
  const float* b2 = (const float*)d_in[9];
  const float* W3 = (const float*)d_in[10];
  const float* U3 = (const float*)d_in[11];
  const float* b3 = (const float*)d_in[12];
  const float* Wd = (const float*)d_in[13];
  const float* bd = (const float*)d_in[14];
  float* outp = (float*)d_out;

  // A: xw0 [M,16] -> xw2 [M,64] -> xw3 [M,70] (73,400,320 B)
  // Bv: xw1 [M,32] -> h2 [M,64]               (67,108,864 B)
  float* A  = (float*)d_ws;
  float* Bv = (float*)((char*)d_ws + 73400320);

  const int M = M_TOTAL;

  // xw0 = x @ W0 + b0
  proj_kernel<78, 16, 4><<<M / 256, 256, 0, stream>>>(x, W0, b0, A, M);
  // scan L0 + fused xw1 = h0 @ W1 + b1
  fused_rec16<<<BB / 4, 64, 0, stream>>>(A, U0, W1, b1, Bv);
  // scan L1 + fused xw2 = h1 @ W2 + b2
  fused_rec32<<<BB / 2, 64, 0, stream>>>(Bv, U1, W2, b2, A);
  // scan L2 -> h2 sequence
  rec64_kernel<<<BB, 64, 0, stream>>>(A, U2, Bv);
  // xw3 = h2 @ W3 + b3
  proj_kernel<64, 70, 18><<<(M + 55) / 56, 256, 0, stream>>>(Bv, W3, b3, A, M);
  // scan L3 (2-wave, slab-staged) + dense + softmax
  rec70_kernel<<<BB, 128, 0, stream>>>(A, U3, Wd, bd, outp);
}